// Round 6
// baseline (1256.448 us; speedup 1.0000x reference)
//
#include <hip/hip_runtime.h>

// Integer softmax (I-BERT shift-exp), S = 2048 per row.
// Key fact: x = fl(k * s_pre) for k in [-128,127] -> only 256 distinct inputs.
// Per row: find kmax (fmax on raw x), build 256-entry LUT of the exact
// reference chain in LDS (4 evals/lane), then per element one rint+gather.
// All LUT arithmetic is bit-identical to the round-1 kernel (absmax 0.0).

#define ROW_S 2048
#define EPL 32            // 2048 / 64 elements per lane
#define WPB 4             // waves per block
#define BT 256

__global__ __launch_bounds__(BT)
void intsoftmax_kernel(const float* __restrict__ x,
                       const float* __restrict__ s_pre_p,
                       float* __restrict__ out,
                       int nrows)
{
    __shared__ float lut[WPB][256];   // 4 KB/block, per-wave private slice

    const int wave = threadIdx.x >> 6;
    const int lane = threadIdx.x & 63;
    const int row  = blockIdx.x * WPB + wave;

    // trailing scalar output: out_sf = 1/2^(BIT_WIDTH-1) = 1/128
    if (blockIdx.x == 0 && threadIdx.x == 0)
        out[(size_t)nrows * ROW_S] = 0.0078125f;
    if (row >= nrows) return;

    const float s_pre = s_pre_p[0];
    const float inv_s = 1.0f / s_pre;            // ONLY for integer index extraction
    const float x0    = floorf(-1.0f / s_pre);   // -20 for s=0.05
    const float nx0   = 15.0f * x0;              // N_SHIFT * x0

    const float* __restrict__ xr   = x   + (size_t)row * ROW_S;
    float*       __restrict__ orow = out + (size_t)row * ROW_S;

    // ---- pass A: load row (float4), track raw-x max (no division!) ----
    float v[EPL];
    float mx = -3.402823466e38f;
    #pragma unroll
    for (int c = 0; c < 8; ++c) {
        float4 f = reinterpret_cast<const float4*>(xr)[c * 64 + lane];
        v[c*4+0] = f.x; v[c*4+1] = f.y; v[c*4+2] = f.z; v[c*4+3] = f.w;
        mx = fmaxf(mx, fmaxf(fmaxf(f.x, f.y), fmaxf(f.z, f.w)));
    }
    #pragma unroll
    for (int off = 32; off; off >>= 1)
        mx = fmaxf(mx, __shfl_xor(mx, off, 64));

    // fl(k*s) is monotone in k -> argmax(x) == kmax; index extraction exact
    const float kmaxf = rintf(mx * inv_s);
    const float m     = (kmaxf * s_pre) / s_pre;   // reference x_int at kmax

    // ---- build per-row LUT (4 entries/lane, bit-identical reference chain) ----
    #pragma unroll
    for (int e = 0; e < 4; ++e) {
        const int idx = e * 64 + lane;             // 0..255, conflict-free writes
        const float kf = (float)(idx - 128);
        const float xi = (kf * s_pre) / s_pre;     // x_int(k), exact replication
        float t = xi - m;
        t = t + floorf(t * 0.5f);                  // x + x>>1 - x>>4
        t = t - floorf(t * 0.0625f);
        t = fmaxf(t, nx0);
        float q = floorf(t / x0);                  // correctly-rounded div, q in [0,15]
        float r = t - x0 * q;                      // x0*q exact -> fma-safe
        float ee = r * 0.5f - x0;
        float p2 = __int_as_float((142 - (int)q) << 23);   // 2^(15-q), exact
        lut[wave][idx] = fmaxf(floorf(ee * p2), 0.0f);
    }
    // same-wave LDS write->read: compiler inserts lgkmcnt wait, no barrier needed

    // ---- pass B: per element k = rint(x*inv_s), gather, exact int sum ----
    int lsum = 0;
    #pragma unroll
    for (int i = 0; i < EPL; ++i) {
        int kk = (int)rintf(v[i] * inv_s) + 128;
        float ei = lut[wave][kk];
        v[i] = ei;
        lsum += (int)ei;                           // ei is an exact small integer
    }
    #pragma unroll
    for (int off = 32; off; off >>= 1)
        lsum += __shfl_xor(lsum, off, 64);
    // max row sum = 2048*655360 = 1.34e9 < 2^31: INT32_MAX clamp never binds

    const float factor = floorf(2147483648.0f / (float)lsum);  // fp32(2^31-1)=2^31
    const float f2 = factor * (1.0f / 16777216.0f);  // exact pow2 scale; fl(ei*f2)
                                                     // == fl(ei*factor)*2^-24
    const float osf = 0.0078125f;                    // 1/128

    // ---- pass C: scale + write (float4) ----
    #pragma unroll
    for (int c = 0; c < 8; ++c) {
        float4 o;
        o.x = floorf(v[c*4+0] * f2) * osf;
        o.y = floorf(v[c*4+1] * f2) * osf;
        o.z = floorf(v[c*4+2] * f2) * osf;
        o.w = floorf(v[c*4+3] * f2) * osf;
        reinterpret_cast<float4*>(orow)[c * 64 + lane] = o;
    }
}

extern "C" void kernel_launch(void* const* d_in, const int* in_sizes, int n_in,
                              void* d_out, int out_size, void* d_ws, size_t ws_size,
                              hipStream_t stream) {
    const float* x     = (const float*)d_in[0];
    const float* s_pre = (const float*)d_in[1];
    float* out = (float*)d_out;

    const int nrows = in_sizes[0] / ROW_S;              // 98304
    const int nblocks = (nrows + WPB - 1) / WPB;

    intsoftmax_kernel<<<nblocks, BT, 0, stream>>>(x, s_pre, out, nrows);
}